// Round 9
// baseline (1589.370 us; speedup 1.0000x reference)
//
#include <hip/hip_runtime.h>

typedef __attribute__((ext_vector_type(8)))  short s8b;      // 8 x bf16
typedef __attribute__((ext_vector_type(8)))  _Float16 f16x8; // 8 x f16
typedef __attribute__((ext_vector_type(16))) float v16f;     // 32x32 f32 acc
typedef __attribute__((ext_vector_type(4)))  float v4f;
typedef __attribute__((ext_vector_type(4)))  unsigned int u32x4;
typedef unsigned short u16;
typedef unsigned int u32;

__device__ __forceinline__ float clamp01(float v) {
  return __builtin_fminf(__builtin_fmaxf(v, 0.0f), 1.0f);   // -> v_med3 ideally
}
__device__ __forceinline__ u16 f16bits(float v) {
  _Float16 h = (_Float16)v;
  return __builtin_bit_cast(u16, h);
}
__device__ __forceinline__ void split1(float f, u16 &h, u16 &l) {
  unsigned u = __builtin_bit_cast(unsigned, f);
  unsigned hu = u & 0xffff0000u;
  float lf = f - __builtin_bit_cast(float, hu);
  h = (u16)(u >> 16);
  l = (u16)(__builtin_bit_cast(unsigned, lf) >> 16);
}

__device__ __forceinline__ v16f mfma32bf(s8b a, s8b b, v16f c) {
  return __builtin_amdgcn_mfma_f32_32x32x16_bf16(a, b, c, 0, 0, 0);
}
__device__ __forceinline__ v16f mfma32h(f16x8 a, f16x8 b, v16f c) {
  return __builtin_amdgcn_mfma_f32_32x32x16_f16(a, b, c, 0, 0, 0);
}
__device__ __forceinline__ v4f mfma16h(f16x8 a, f16x8 b, v4f c) {
  return __builtin_amdgcn_mfma_f32_16x16x32_f16(a, b, c, 0, 0, 0);
}

// swizzled u16 index in a [R][256] tile: 8-elem chunk c=col>>3 -> c^(row&7)
__device__ __forceinline__ int sw_idx(int row, int col) {
  return row * 256 + ((((col >> 3) ^ (row & 7))) << 3) + (col & 7);
}

// ---------------- prep kernels ----------------------------------------------
// W2/W3 -> f16 frag chunks: chunk i=(w*16+kt)*64+l holds 8 f16:
//   col=(w*32+(l&31)), k=kt*16+(l>>5)*8 .. +7
// W0 -> [16][256] f16 (n<10 valid); W4 -> bf16 h/l (for k_drive)
__global__ void k_prep_w(const float* __restrict__ W2, const float* __restrict__ W3,
                         const float* __restrict__ W4, const float* __restrict__ W0,
                         u16* __restrict__ w2f, u16* __restrict__ w3f,
                         u16* __restrict__ w0f,
                         u16* __restrict__ w4h, u16* __restrict__ w4l) {
  int i = blockIdx.x * 256 + threadIdx.x;
  if (i < 8192) {     // fragment chunks
    int w = i >> 10, kt = (i >> 6) & 15, l = i & 63;
    int m = l & 31, g = l >> 5;
    int src = (w * 32 + m) * 256 + kt * 16 + g * 8;
    u16 a2[8], a3[8];
    #pragma unroll
    for (int j = 0; j < 8; ++j) {
      a2[j] = f16bits(W2[src + j]);
      a3[j] = f16bits(W3[src + j]);
    }
    #pragma unroll
    for (int j = 0; j < 8; ++j) { w2f[i * 8 + j] = a2[j]; w3f[i * 8 + j] = a3[j]; }
  }
  if (i < 4096) {                           // W0 padded [16][256]
    int n = i >> 8, k = i & 255;
    float v = (n < 10) ? W0[n * 256 + k] : 0.0f;
    w0f[i] = f16bits(v);
  }
  if (i < 200704) {
    u16 h, lo;
    split1(W4[i], h, lo); w4h[i] = h; w4l[i] = lo;
  }
}

// W1 frags: chunk i=w*64+l holds 8 f16: col=w*32+(l&31), k=(l>>5)*8+j (k<10 valid)
__global__ void k_prep_small(const float* __restrict__ W1, const float* __restrict__ b0,
                             u16* __restrict__ w1f, float* __restrict__ b0p) {
  int i = blockIdx.x * 256 + threadIdx.x;
  if (i < 512) {
    int w = i >> 6, l = i & 63, m = l & 31, g = l >> 5;
    int col = w * 32 + m;
    #pragma unroll
    for (int j = 0; j < 8; ++j) {
      int k = g * 8 + j;
      float f = (k < 10) ? W1[col * 10 + k] : 0.0f;
      w1f[i * 8 + j] = f16bits(f);
    }
  } else if (i < 528) {
    int k = i - 512;
    b0p[k] = (k < 10) ? b0[k] : 0.0f;
  }
}

// ---------------- drive = data @ W4^T + b4 (bf16 3-pass, once) ---------------
__device__ __forceinline__ void split_pack8(v4f x0, v4f x1, s8b &hi, s8b &lo) {
  float f[8];
  #pragma unroll
  for (int j = 0; j < 4; ++j) { f[j] = x0[j]; f[4 + j] = x1[j]; }
  u32x4 vh, vl;
  #pragma unroll
  for (int j = 0; j < 4; ++j) {
    unsigned u0 = __builtin_bit_cast(unsigned, f[2 * j]);
    unsigned u1 = __builtin_bit_cast(unsigned, f[2 * j + 1]);
    unsigned h0 = u0 & 0xffff0000u, h1 = u1 & 0xffff0000u;
    float l0 = f[2 * j]     - __builtin_bit_cast(float, h0);
    float l1 = f[2 * j + 1] - __builtin_bit_cast(float, h1);
    vh[j] = (u0 >> 16) | h1;
    vl[j] = (__builtin_bit_cast(unsigned, l0) >> 16) |
            (__builtin_bit_cast(unsigned, l1) & 0xffff0000u);
  }
  hi = __builtin_bit_cast(s8b, vh);
  lo = __builtin_bit_cast(s8b, vl);
}

__global__ void __launch_bounds__(256, 1) k_drive(
    const float* __restrict__ data, const u16* __restrict__ w4h,
    const u16* __restrict__ w4l, const float* __restrict__ b4,
    float* __restrict__ drive) {
  const int tid = threadIdx.x;
  const int w = tid >> 6, l = tid & 63;
  const int m = l & 31, g = l >> 5;
  const int rb = blockIdx.x * 64;
  const int nbase = w * 64;
  float b4v0 = b4[nbase + m], b4v1 = b4[nbase + 32 + m];
  v16f acc[2][2];
  #pragma unroll
  for (int r = 0; r < 16; ++r) {
    acc[0][0][r] = b4v0; acc[0][1][r] = b4v1;
    acc[1][0][r] = b4v0; acc[1][1][r] = b4v1;
  }
  for (int kt = 0; kt < 49; ++kt) {
    int k0 = kt * 16 + g * 8;
    s8b aH[2], aL[2], bH[2], bL[2];
    #pragma unroll
    for (int mt = 0; mt < 2; ++mt) {
      const float* p = data + (size_t)(rb + 32 * mt + m) * 784 + k0;
      v4f x0 = *(const v4f*)p;
      v4f x1 = *(const v4f*)(p + 4);
      split_pack8(x0, x1, aH[mt], aL[mt]);
    }
    #pragma unroll
    for (int nt = 0; nt < 2; ++nt) {
      int off = (nbase + 32 * nt + m) * 784 + k0;
      bH[nt] = *(const s8b*)(w4h + off);
      bL[nt] = *(const s8b*)(w4l + off);
    }
    #pragma unroll
    for (int mt = 0; mt < 2; ++mt)
      #pragma unroll
      for (int nt = 0; nt < 2; ++nt) {
        acc[mt][nt] = mfma32bf(aH[mt], bH[nt], acc[mt][nt]);
        acc[mt][nt] = mfma32bf(aL[mt], bH[nt], acc[mt][nt]);
        acc[mt][nt] = mfma32bf(aH[mt], bL[nt], acc[mt][nt]);
      }
  }
  #pragma unroll
  for (int mt = 0; mt < 2; ++mt)
    #pragma unroll
    for (int nt = 0; nt < 2; ++nt)
      #pragma unroll
      for (int r = 0; r < 16; ++r) {
        int row = rb + 32 * mt + (r & 3) + 8 * (r >> 2) + 4 * g;
        int col = nbase + 32 * nt + m;
        drive[(size_t)row * 256 + col] = acc[mt][nt][r];
      }
}

// ---------------- main persistent stepper (f16 single-pass) ------------------
__global__ void __launch_bounds__(512, 2) k_main(
    const float* __restrict__ s0g, const float* __restrict__ s1g,
    const float* __restrict__ s2g, const float* __restrict__ b2,
    const int* __restrict__ Tp,
    const u16* __restrict__ w2f, const u16* __restrict__ w3f,
    const u16* __restrict__ w0f, const u16* __restrict__ w1f,
    const float* __restrict__ b0p, const float* __restrict__ drive,
    float* __restrict__ out0, float* __restrict__ out1, float* __restrict__ out2) {
  extern __shared__ u16 smem[];
  u16* s1A = smem;                  // [64][256] f16 swizzled, 32 KB each
  u16* s1B = smem + 16384;
  u16* s2A = smem + 32768;
  u16* s2B = smem + 49152;
  u16* s0A = smem + 65536;          // [64][16] f16, 2 KB each
  u16* s0B = smem + 66560;
  u16* w0s = smem + 67584;          // [16][256] f16 swizzled, 8 KB
  // total 71680 u16 = 143360 B

  const int tid = threadIdx.x;
  const int w = tid >> 6, l = tid & 63;
  const int m = l & 31, g = l >> 5;
  const int m16 = l & 15, g4 = l >> 4;
  const int rb = blockIdx.x * 64;
  const int nbase = w * 32;
  const int col = nbase + m;

  // ---- stage weights into registers (once): 128 VGPR + 4 ----
  f16x8 w2F[16], w3F[16];
  {
    const int cb = (w * 16) * 64 + l;     // chunk base
    #pragma unroll
    for (int kt = 0; kt < 16; ++kt) {
      w2F[kt] = *(const f16x8*)(w2f + (cb + kt * 64) * 8);
      w3F[kt] = *(const f16x8*)(w3f + (cb + kt * 64) * 8);
    }
  }
  const f16x8 w1F = *(const f16x8*)(w1f + (w * 64 + l) * 8);

  // ---- init LDS states ----
  for (int i = tid; i < 16384; i += 512) {
    int row = i >> 8, c = i & 255;
    int idx = sw_idx(row, c);
    s1A[idx] = f16bits(s1g[(size_t)(rb + row) * 256 + c]);
    s2A[idx] = f16bits(s2g[(size_t)(rb + row) * 256 + c]);
  }
  for (int i = tid; i < 1024; i += 512) {
    int row = i >> 4, c = i & 15;
    float v = (c < 10) ? s0g[(rb + row) * 10 + c] : 0.0f;
    s0A[i] = f16bits(v);
    s0B[i] = 0;                     // f16 zero
  }
  if (tid < 512) {                  // stage W0 into LDS, swizzled 8-elem chunks
    int r = tid >> 5, c = tid & 31;
    int dst = r * 256 + ((c ^ (r & 7)) << 3);
    #pragma unroll
    for (int j = 0; j < 8; ++j) w0s[dst + j] = w0f[r * 256 + c * 8 + j];
  }

  const float b2v = b2[col];
  const float b0v = b0p[m16];
  float dr[2][16];
  #pragma unroll
  for (int mt = 0; mt < 2; ++mt)
    #pragma unroll
    for (int r = 0; r < 16; ++r) {
      int row = rb + 32 * mt + (r & 3) + 8 * (r >> 2) + 4 * g;
      dr[mt][r] = drive[(size_t)row * 256 + col];
    }
  const int T = Tp[0];
  const int cq = col >> 3, cw = col & 7;
  const int rs = (m & 7) << 3;      // A-read swizzle shift ((m+32)&7 == m&7)
  __syncthreads();

  u16 *s1c = s1A, *s1n = s1B, *s2c = s2A, *s2n = s2B;
  u16 *s0c = s0A, *s0n = s0B;

  for (int t = 0; t < T; ++t) {
    const bool last = (t == T - 1);

    // ---- n2 = clamp(drive + s1 @ W3^T) ----
    v16f acc2[2];
    #pragma unroll
    for (int r = 0; r < 16; ++r) { acc2[0][r] = dr[0][r]; acc2[1][r] = dr[1][r]; }
    {
      const u16* a0p = s1c + m * 256;
      const u16* a1p = s1c + (m + 32) * 256;
      #pragma unroll
      for (int kt = 0; kt < 16; ++kt) {
        const int off = ((2 * kt + g) << 3) ^ rs;
        f16x8 a0 = *(const f16x8*)(a0p + off);
        f16x8 a1 = *(const f16x8*)(a1p + off);
        acc2[0] = mfma32h(a0, w3F[kt], acc2[0]);
        acc2[1] = mfma32h(a1, w3F[kt], acc2[1]);
      }
    }
    #pragma unroll
    for (int mt = 0; mt < 2; ++mt)
      #pragma unroll
      for (int r = 0; r < 16; ++r) {
        float v = clamp01(acc2[mt][r]);
        int row = 32 * mt + (r & 3) + 8 * (r >> 2) + 4 * g;
        s2n[row * 256 + ((cq ^ (row & 7)) << 3) + cw] = f16bits(v);
        if (last) out2[(size_t)(rb + row) * 256 + col] = v;
      }

    // ---- n1 = clamp(b2 + s0 @ W1^T + s2 @ W2^T) ----
    v16f acc1[2];
    #pragma unroll
    for (int r = 0; r < 16; ++r) { acc1[0][r] = b2v; acc1[1][r] = b2v; }
    {
      f16x8 a0s = *(const f16x8*)(s0c + m * 16 + g * 8);
      f16x8 a1s = *(const f16x8*)(s0c + (m + 32) * 16 + g * 8);
      acc1[0] = mfma32h(a0s, w1F, acc1[0]);
      acc1[1] = mfma32h(a1s, w1F, acc1[1]);
      const u16* a0p = s2c + m * 256;
      const u16* a1p = s2c + (m + 32) * 256;
      #pragma unroll
      for (int kt = 0; kt < 16; ++kt) {
        const int off = ((2 * kt + g) << 3) ^ rs;
        f16x8 a0 = *(const f16x8*)(a0p + off);
        f16x8 a1 = *(const f16x8*)(a1p + off);
        acc1[0] = mfma32h(a0, w2F[kt], acc1[0]);
        acc1[1] = mfma32h(a1, w2F[kt], acc1[1]);
      }
    }
    #pragma unroll
    for (int mt = 0; mt < 2; ++mt)
      #pragma unroll
      for (int r = 0; r < 16; ++r) {
        float v = clamp01(acc1[mt][r]);
        int row = 32 * mt + (r & 3) + 8 * (r >> 2) + 4 * g;
        s1n[row * 256 + ((cq ^ (row & 7)) << 3) + cw] = f16bits(v);
        if (last) out1[(size_t)(rb + row) * 256 + col] = v;
      }

    // ---- n0 = clamp(b0 + s1 @ W0^T), waves 0-3, 16x16x32 f16 ----
    if (w < 4) {
      const int arow = 16 * w + m16;
      const int rsh = (arow & 7) << 3;
      const u16* ap = s1c + arow * 256;
      v4f acc0;
      #pragma unroll
      for (int r = 0; r < 4; ++r) acc0[r] = b0v;
      #pragma unroll
      for (int kt = 0; kt < 8; ++kt) {
        const int ch = 4 * kt + g4;
        f16x8 a = *(const f16x8*)(ap + ((ch << 3) ^ rsh));
        f16x8 b = *(const f16x8*)(w0s + m16 * 256 + ((ch ^ (m16 & 7)) << 3));
        acc0 = mfma16h(a, b, acc0);
      }
      #pragma unroll
      for (int r = 0; r < 4; ++r) {
        float v = clamp01(acc0[r]);
        int row = 16 * w + g4 * 4 + r;
        if (m16 < 10) {
          s0n[row * 16 + m16] = f16bits(v);
          if (last) out0[(rb + row) * 10 + m16] = v;
        }
      }
    }

    __syncthreads();   // next-state buffers fully written; old fully read
    u16* tp;
    tp = s1c; s1c = s1n; s1n = tp;
    tp = s2c; s2c = s2n; s2n = tp;
    tp = s0c; s0c = s0n; s0n = tp;
  }
}

// ---------------- launcher ---------------------------------------------------
extern "C" void kernel_launch(void* const* d_in, const int* in_sizes, int n_in,
                              void* d_out, int out_size, void* d_ws, size_t ws_size,
                              hipStream_t stream) {
  const float* data = (const float*)d_in[0];
  const float* s0g  = (const float*)d_in[1];
  const float* s1g  = (const float*)d_in[2];
  const float* s2g  = (const float*)d_in[3];
  const float* W0   = (const float*)d_in[4];
  const float* b0   = (const float*)d_in[5];
  const float* W1   = (const float*)d_in[6];
  const float* W2   = (const float*)d_in[7];
  const float* b2   = (const float*)d_in[8];
  const float* W3   = (const float*)d_in[9];
  const float* W4   = (const float*)d_in[10];
  const float* b4   = (const float*)d_in[11];
  const int*   Tp   = (const int*)d_in[12];

  char* ws = (char*)d_ws;
  float* drive = (float*)ws;                                  // 16 MB f32
  size_t off = 16777216;
  u16* w2f = (u16*)(ws + off); off += 131072;
  u16* w3f = (u16*)(ws + off); off += 131072;
  u16* w0f = (u16*)(ws + off); off += 8192;
  u16* w1f = (u16*)(ws + off); off += 8192;
  u16* w4h = (u16*)(ws + off); off += 401408;
  u16* w4l = (u16*)(ws + off); off += 401408;
  float* b0p = (float*)(ws + off); off += 64;

  float* out0 = (float*)d_out;
  float* out1 = out0 + 16384 * 10;
  float* out2 = out1 + 16384 * 256;

  hipFuncSetAttribute((const void*)k_main,
                      hipFuncAttributeMaxDynamicSharedMemorySize, 143360);

  k_prep_w<<<784, 256, 0, stream>>>(W2, W3, W4, W0, w2f, w3f, w0f, w4h, w4l);
  k_prep_small<<<3, 256, 0, stream>>>(W1, b0, w1f, b0p);
  k_drive<<<256, 256, 0, stream>>>(data, w4h, w4l, b4, drive);
  k_main<<<256, 512, 143360, stream>>>(s0g, s1g, s2g, b2, Tp,
      w2f, w3f, w0f, w1f, b0p, drive, out0, out1, out2);
}

// Round 10
// 1244.156 us; speedup vs baseline: 1.2775x; 1.2775x over previous
//
#include <hip/hip_runtime.h>

typedef __attribute__((ext_vector_type(8)))  short s8b;      // 8 x bf16
typedef __attribute__((ext_vector_type(8)))  _Float16 f16x8; // 8 x f16
typedef __attribute__((ext_vector_type(16))) float v16f;     // 32x32 f32 acc
typedef __attribute__((ext_vector_type(4)))  float v4f;
typedef __attribute__((ext_vector_type(4)))  unsigned int u32x4;
typedef unsigned short u16;
typedef unsigned int u32;

__device__ __forceinline__ float clamp01(float v) {
  return __builtin_fminf(__builtin_fmaxf(v, 0.0f), 1.0f);
}
__device__ __forceinline__ u16 f16bits(float v) {
  _Float16 h = (_Float16)v;
  return __builtin_bit_cast(u16, h);
}
__device__ __forceinline__ void split1(float f, u16 &h, u16 &l) {
  unsigned u = __builtin_bit_cast(unsigned, f);
  unsigned hu = u & 0xffff0000u;
  float lf = f - __builtin_bit_cast(float, hu);
  h = (u16)(u >> 16);
  l = (u16)(__builtin_bit_cast(unsigned, lf) >> 16);
}

__device__ __forceinline__ v16f mfma32bf(s8b a, s8b b, v16f c) {
  return __builtin_amdgcn_mfma_f32_32x32x16_bf16(a, b, c, 0, 0, 0);
}
__device__ __forceinline__ v16f mfma32h(f16x8 a, f16x8 b, v16f c) {
  return __builtin_amdgcn_mfma_f32_32x32x16_f16(a, b, c, 0, 0, 0);
}
__device__ __forceinline__ v4f mfma16h(f16x8 a, f16x8 b, v4f c) {
  return __builtin_amdgcn_mfma_f32_16x16x32_f16(a, b, c, 0, 0, 0);
}

// swizzled u16 index in a [R][256] tile: 8-elem chunk c=col>>3 -> c^(row&7)
__device__ __forceinline__ int sw_idx(int row, int col) {
  return row * 256 + ((((col >> 3) ^ (row & 7))) << 3) + (col & 7);
}

// ---------------- prep kernels ----------------------------------------------
// W2/W3 -> f16 frag chunks: chunk i=(w*16+kt)*64+l holds 8 f16:
//   col=(w*32+(l&31)), k=kt*16+(l>>5)*8 .. +7
// W0 -> [16][256] f16 (n<10 valid); W4 -> bf16 h/l (for k_drive)
__global__ void k_prep_w(const float* __restrict__ W2, const float* __restrict__ W3,
                         const float* __restrict__ W4, const float* __restrict__ W0,
                         u16* __restrict__ w2f, u16* __restrict__ w3f,
                         u16* __restrict__ w0f,
                         u16* __restrict__ w4h, u16* __restrict__ w4l) {
  int i = blockIdx.x * 256 + threadIdx.x;
  if (i < 8192) {     // fragment chunks
    int w = i >> 10, kt = (i >> 6) & 15, l = i & 63;
    int m = l & 31, g = l >> 5;
    int src = (w * 32 + m) * 256 + kt * 16 + g * 8;
    u16 a2[8], a3[8];
    #pragma unroll
    for (int j = 0; j < 8; ++j) {
      a2[j] = f16bits(W2[src + j]);
      a3[j] = f16bits(W3[src + j]);
    }
    #pragma unroll
    for (int j = 0; j < 8; ++j) { w2f[i * 8 + j] = a2[j]; w3f[i * 8 + j] = a3[j]; }
  }
  if (i < 4096) {                           // W0 padded [16][256]
    int n = i >> 8, k = i & 255;
    float v = (n < 10) ? W0[n * 256 + k] : 0.0f;
    w0f[i] = f16bits(v);
  }
  if (i < 200704) {
    u16 h, lo;
    split1(W4[i], h, lo); w4h[i] = h; w4l[i] = lo;
  }
}

// W1 frags: chunk i=w*64+l holds 8 f16: col=w*32+(l&31), k=(l>>5)*8+j (k<10 valid)
__global__ void k_prep_small(const float* __restrict__ W1, const float* __restrict__ b0,
                             u16* __restrict__ w1f, float* __restrict__ b0p) {
  int i = blockIdx.x * 256 + threadIdx.x;
  if (i < 512) {
    int w = i >> 6, l = i & 63, m = l & 31, g = l >> 5;
    int col = w * 32 + m;
    #pragma unroll
    for (int j = 0; j < 8; ++j) {
      int k = g * 8 + j;
      float f = (k < 10) ? W1[col * 10 + k] : 0.0f;
      w1f[i * 8 + j] = f16bits(f);
    }
  } else if (i < 528) {
    int k = i - 512;
    b0p[k] = (k < 10) ? b0[k] : 0.0f;
  }
}

// ---------------- drive = data @ W4^T + b4 (bf16 3-pass, once) ---------------
__device__ __forceinline__ void split_pack8(v4f x0, v4f x1, s8b &hi, s8b &lo) {
  float f[8];
  #pragma unroll
  for (int j = 0; j < 4; ++j) { f[j] = x0[j]; f[4 + j] = x1[j]; }
  u32x4 vh, vl;
  #pragma unroll
  for (int j = 0; j < 4; ++j) {
    unsigned u0 = __builtin_bit_cast(unsigned, f[2 * j]);
    unsigned u1 = __builtin_bit_cast(unsigned, f[2 * j + 1]);
    unsigned h0 = u0 & 0xffff0000u, h1 = u1 & 0xffff0000u;
    float l0 = f[2 * j]     - __builtin_bit_cast(float, h0);
    float l1 = f[2 * j + 1] - __builtin_bit_cast(float, h1);
    vh[j] = (u0 >> 16) | h1;
    vl[j] = (__builtin_bit_cast(unsigned, l0) >> 16) |
            (__builtin_bit_cast(unsigned, l1) & 0xffff0000u);
  }
  hi = __builtin_bit_cast(s8b, vh);
  lo = __builtin_bit_cast(s8b, vl);
}

__global__ void __launch_bounds__(256, 1) k_drive(
    const float* __restrict__ data, const u16* __restrict__ w4h,
    const u16* __restrict__ w4l, const float* __restrict__ b4,
    float* __restrict__ drive) {
  const int tid = threadIdx.x;
  const int w = tid >> 6, l = tid & 63;
  const int m = l & 31, g = l >> 5;
  const int rb = blockIdx.x * 64;
  const int nbase = w * 64;
  float b4v0 = b4[nbase + m], b4v1 = b4[nbase + 32 + m];
  v16f acc[2][2];
  #pragma unroll
  for (int r = 0; r < 16; ++r) {
    acc[0][0][r] = b4v0; acc[0][1][r] = b4v1;
    acc[1][0][r] = b4v0; acc[1][1][r] = b4v1;
  }
  for (int kt = 0; kt < 49; ++kt) {
    int k0 = kt * 16 + g * 8;
    s8b aH[2], aL[2], bH[2], bL[2];
    #pragma unroll
    for (int mt = 0; mt < 2; ++mt) {
      const float* p = data + (size_t)(rb + 32 * mt + m) * 784 + k0;
      v4f x0 = *(const v4f*)p;
      v4f x1 = *(const v4f*)(p + 4);
      split_pack8(x0, x1, aH[mt], aL[mt]);
    }
    #pragma unroll
    for (int nt = 0; nt < 2; ++nt) {
      int off = (nbase + 32 * nt + m) * 784 + k0;
      bH[nt] = *(const s8b*)(w4h + off);
      bL[nt] = *(const s8b*)(w4l + off);
    }
    #pragma unroll
    for (int mt = 0; mt < 2; ++mt)
      #pragma unroll
      for (int nt = 0; nt < 2; ++nt) {
        acc[mt][nt] = mfma32bf(aH[mt], bH[nt], acc[mt][nt]);
        acc[mt][nt] = mfma32bf(aL[mt], bH[nt], acc[mt][nt]);
        acc[mt][nt] = mfma32bf(aH[mt], bL[nt], acc[mt][nt]);
      }
  }
  #pragma unroll
  for (int mt = 0; mt < 2; ++mt)
    #pragma unroll
    for (int nt = 0; nt < 2; ++nt)
      #pragma unroll
      for (int r = 0; r < 16; ++r) {
        int row = rb + 32 * mt + (r & 3) + 8 * (r >> 2) + 4 * g;
        int col = nbase + 32 * nt + m;
        drive[(size_t)row * 256 + col] = acc[mt][nt][r];
      }
}

// ---------------- main persistent stepper (f16, L2-streamed weights) ---------
__global__ void __launch_bounds__(512, 2) k_main(
    const float* __restrict__ s0g, const float* __restrict__ s1g,
    const float* __restrict__ s2g, const float* __restrict__ b2,
    const int* __restrict__ Tp,
    const u16* __restrict__ w2f, const u16* __restrict__ w3f,
    const u16* __restrict__ w0f, const u16* __restrict__ w1f,
    const float* __restrict__ b0p, const float* __restrict__ drive,
    float* __restrict__ out0, float* __restrict__ out1, float* __restrict__ out2) {
  extern __shared__ u16 smem[];
  u16* s1A = smem;                  // [64][256] f16 swizzled, 32 KB each
  u16* s1B = smem + 16384;
  u16* s2A = smem + 32768;
  u16* s2B = smem + 49152;
  u16* s0A = smem + 65536;          // [64][16] f16, 2 KB each
  u16* s0B = smem + 66560;
  u16* w0s = smem + 67584;          // [16][256] f16 swizzled, 8 KB
  // total 71680 u16 = 143360 B

  const int tid = threadIdx.x;
  const int w = tid >> 6, l = tid & 63;
  const int m = l & 31, g = l >> 5;
  const int m16 = l & 15, g4 = l >> 4;
  const int rb = blockIdx.x * 64;
  const int nbase = w * 32;
  const int col = nbase + m;

  // streamed-weight per-lane base pointers (fragment order, L2-resident)
  const u16* wp2 = w2f + (w << 13) + (l << 3);   // + kt*512 per kt
  const u16* wp3 = w3f + (w << 13) + (l << 3);
  const f16x8 w1F = *(const f16x8*)(w1f + ((w << 6) + l) * 8);

  // ---- init LDS states ----
  for (int i = tid; i < 16384; i += 512) {
    int row = i >> 8, c = i & 255;
    int idx = sw_idx(row, c);
    s1A[idx] = f16bits(s1g[(size_t)(rb + row) * 256 + c]);
    s2A[idx] = f16bits(s2g[(size_t)(rb + row) * 256 + c]);
  }
  for (int i = tid; i < 1024; i += 512) {
    int row = i >> 4, c = i & 15;
    float v = (c < 10) ? s0g[(rb + row) * 10 + c] : 0.0f;
    s0A[i] = f16bits(v);
    s0B[i] = 0;                     // f16 zero
  }
  if (tid < 512) {                  // stage W0 into LDS, swizzled 8-elem chunks
    int r = tid >> 5, c = tid & 31;
    int dst = r * 256 + ((c ^ (r & 7)) << 3);
    #pragma unroll
    for (int j = 0; j < 8; ++j) w0s[dst + j] = w0f[r * 256 + c * 8 + j];
  }

  const float b2v = b2[col];
  const float b0v = b0p[m16];
  float dr[2][16];
  #pragma unroll
  for (int mt = 0; mt < 2; ++mt)
    #pragma unroll
    for (int r = 0; r < 16; ++r) {
      int row = rb + 32 * mt + (r & 3) + 8 * (r >> 2) + 4 * g;
      dr[mt][r] = drive[(size_t)row * 256 + col];
    }
  const int T = Tp[0];
  const int cq = col >> 3, cw = col & 7;
  const int rs = (m & 7) << 3;      // A-read swizzle shift ((m+32)&7 == m&7)
  __syncthreads();

  u16 *s1c = s1A, *s1n = s1B, *s2c = s2A, *s2n = s2B;
  u16 *s0c = s0A, *s0n = s0B;

  for (int t = 0; t < T; ++t) {
    const bool last = (t == T - 1);

    // ---- n2 = clamp(drive + s1 @ W3^T) ----   (W3 frags streamed, depth-8 ring)
    v16f acc2[2];
    #pragma unroll
    for (int r = 0; r < 16; ++r) { acc2[0][r] = dr[0][r]; acc2[1][r] = dr[1][r]; }
    {
      f16x8 b3[8];
      #pragma unroll
      for (int i = 0; i < 8; ++i) b3[i] = *(const f16x8*)(wp3 + i * 512);
      const u16* a0p = s1c + m * 256;
      const u16* a1p = s1c + (m + 32) * 256;
      #pragma unroll
      for (int kt = 0; kt < 16; ++kt) {
        const int off = ((2 * kt + g) << 3) ^ rs;
        f16x8 a0 = *(const f16x8*)(a0p + off);
        f16x8 a1 = *(const f16x8*)(a1p + off);
        f16x8 bb = b3[kt & 7];
        if (kt < 8) b3[kt & 7] = *(const f16x8*)(wp3 + (kt + 8) * 512);
        acc2[0] = mfma32h(a0, bb, acc2[0]);
        acc2[1] = mfma32h(a1, bb, acc2[1]);
      }
    }
    // issue first half of W2 ring before the n2 epilogue (hide L2 latency)
    f16x8 b2r[8];
    #pragma unroll
    for (int i = 0; i < 8; ++i) b2r[i] = *(const f16x8*)(wp2 + i * 512);

    #pragma unroll
    for (int mt = 0; mt < 2; ++mt)
      #pragma unroll
      for (int r = 0; r < 16; ++r) {
        float v = clamp01(acc2[mt][r]);
        int row = 32 * mt + (r & 3) + 8 * (r >> 2) + 4 * g;
        s2n[row * 256 + ((cq ^ (row & 7)) << 3) + cw] = f16bits(v);
        if (last) out2[(size_t)(rb + row) * 256 + col] = v;
      }

    // ---- n1 = clamp(b2 + s0 @ W1^T + s2 @ W2^T) ----
    v16f acc1[2];
    #pragma unroll
    for (int r = 0; r < 16; ++r) { acc1[0][r] = b2v; acc1[1][r] = b2v; }
    {
      f16x8 a0s = *(const f16x8*)(s0c + m * 16 + g * 8);
      f16x8 a1s = *(const f16x8*)(s0c + (m + 32) * 16 + g * 8);
      acc1[0] = mfma32h(a0s, w1F, acc1[0]);
      acc1[1] = mfma32h(a1s, w1F, acc1[1]);
      const u16* a0p = s2c + m * 256;
      const u16* a1p = s2c + (m + 32) * 256;
      #pragma unroll
      for (int kt = 0; kt < 16; ++kt) {
        const int off = ((2 * kt + g) << 3) ^ rs;
        f16x8 a0 = *(const f16x8*)(a0p + off);
        f16x8 a1 = *(const f16x8*)(a1p + off);
        f16x8 bb = b2r[kt & 7];
        if (kt < 8) b2r[kt & 7] = *(const f16x8*)(wp2 + (kt + 8) * 512);
        acc1[0] = mfma32h(a0, bb, acc1[0]);
        acc1[1] = mfma32h(a1, bb, acc1[1]);
      }
    }
    #pragma unroll
    for (int mt = 0; mt < 2; ++mt)
      #pragma unroll
      for (int r = 0; r < 16; ++r) {
        float v = clamp01(acc1[mt][r]);
        int row = 32 * mt + (r & 3) + 8 * (r >> 2) + 4 * g;
        s1n[row * 256 + ((cq ^ (row & 7)) << 3) + cw] = f16bits(v);
        if (last) out1[(size_t)(rb + row) * 256 + col] = v;
      }

    // ---- n0 = clamp(b0 + s1 @ W0^T), waves 0-3, 16x16x32 f16 ----
    if (w < 4) {
      const int arow = 16 * w + m16;
      const int rsh = (arow & 7) << 3;
      const u16* ap = s1c + arow * 256;
      v4f acc0;
      #pragma unroll
      for (int r = 0; r < 4; ++r) acc0[r] = b0v;
      #pragma unroll
      for (int kt = 0; kt < 8; ++kt) {
        const int ch = 4 * kt + g4;
        f16x8 a = *(const f16x8*)(ap + ((ch << 3) ^ rsh));
        f16x8 b = *(const f16x8*)(w0s + m16 * 256 + ((ch ^ (m16 & 7)) << 3));
        acc0 = mfma16h(a, b, acc0);
      }
      #pragma unroll
      for (int r = 0; r < 4; ++r) {
        float v = clamp01(acc0[r]);
        int row = 16 * w + g4 * 4 + r;
        if (m16 < 10) {
          s0n[row * 16 + m16] = f16bits(v);
          if (last) out0[(rb + row) * 10 + m16] = v;
        }
      }
    }

    __syncthreads();   // next-state buffers fully written; old fully read
    u16* tp;
    tp = s1c; s1c = s1n; s1n = tp;
    tp = s2c; s2c = s2n; s2n = tp;
    tp = s0c; s0c = s0n; s0n = tp;
  }
}

// ---------------- launcher ---------------------------------------------------
extern "C" void kernel_launch(void* const* d_in, const int* in_sizes, int n_in,
                              void* d_out, int out_size, void* d_ws, size_t ws_size,
                              hipStream_t stream) {
  const float* data = (const float*)d_in[0];
  const float* s0g  = (const float*)d_in[1];
  const float* s1g  = (const float*)d_in[2];
  const float* s2g  = (const float*)d_in[3];
  const float* W0   = (const float*)d_in[4];
  const float* b0   = (const float*)d_in[5];
  const float* W1   = (const float*)d_in[6];
  const float* W2   = (const float*)d_in[7];
  const float* b2   = (const float*)d_in[8];
  const float* W3   = (const float*)d_in[9];
  const float* W4   = (const float*)d_in[10];
  const float* b4   = (const float*)d_in[11];
  const int*   Tp   = (const int*)d_in[12];

  char* ws = (char*)d_ws;
  float* drive = (float*)ws;                                  // 16 MB f32
  size_t off = 16777216;
  u16* w2f = (u16*)(ws + off); off += 131072;
  u16* w3f = (u16*)(ws + off); off += 131072;
  u16* w0f = (u16*)(ws + off); off += 8192;
  u16* w1f = (u16*)(ws + off); off += 8192;
  u16* w4h = (u16*)(ws + off); off += 401408;
  u16* w4l = (u16*)(ws + off); off += 401408;
  float* b0p = (float*)(ws + off); off += 64;

  float* out0 = (float*)d_out;
  float* out1 = out0 + 16384 * 10;
  float* out2 = out1 + 16384 * 256;

  hipFuncSetAttribute((const void*)k_main,
                      hipFuncAttributeMaxDynamicSharedMemorySize, 143360);

  k_prep_w<<<784, 256, 0, stream>>>(W2, W3, W4, W0, w2f, w3f, w0f, w4h, w4l);
  k_prep_small<<<3, 256, 0, stream>>>(W1, b0, w1f, b0p);
  k_drive<<<256, 256, 0, stream>>>(data, w4h, w4l, b4, drive);
  k_main<<<256, 512, 143360, stream>>>(s0g, s1g, s2g, b2, Tp,
      w2f, w3f, w0f, w1f, b0p, drive, out0, out1, out2);
}